// Round 8
// baseline (262.467 us; speedup 1.0000x reference)
//
#include <hip/hip_runtime.h>
#include <cstdint>
#include <cstddef>

// ---------- types & helpers ----------
typedef __bf16 bf16x8 __attribute__((ext_vector_type(8)));
typedef float f32x4 __attribute__((ext_vector_type(4)));
typedef unsigned short u16;
typedef unsigned short u16x8 __attribute__((ext_vector_type(8)));
typedef unsigned int u32;

typedef __attribute__((address_space(1))) void gvoid_t;
typedef __attribute__((address_space(3))) void lvoid_t;

// async global->LDS, 16B per lane. LDS dest = wave-uniform base + lane*16.
__device__ __forceinline__ void gld_lds16(const void* g, void* l) {
  __builtin_amdgcn_global_load_lds((gvoid_t*)g, (lvoid_t*)l, 16, 0, 0);
}

__device__ __forceinline__ u16 f2bf(float f) {
  u32 u = __float_as_uint(f);
  u += 0x7fffu + ((u >> 16) & 1u);   // RNE
  return (u16)(u >> 16);
}
// packed f32x2 -> bf16x2 via v_perm_b32, half-up rounding: 3 VALU ops total
__device__ __forceinline__ u32 pack_rnd(float a, float b) {
  const u32 ua = __float_as_uint(a) + 0x8000u;
  const u32 ub = __float_as_uint(b) + 0x8000u;
  return __builtin_amdgcn_perm(ub, ua, 0x07060302u);  // [ub.hi16 : ua.hi16]
}
__device__ __forceinline__ bf16x8 ld_frag(const u16* p) {
  return __builtin_bit_cast(bf16x8, *(const uint4*)p);
}
__device__ __forceinline__ f32x4 mfma16(bf16x8 a, bf16x8 b, f32x4 c) {
  return __builtin_amdgcn_mfma_f32_16x16x32_bf16(a, b, c, 0, 0, 0);
}
// 2^x via v_exp_f32 (single instruction)
__device__ __forceinline__ float ex2(float x) {
  return __builtin_amdgcn_exp2f(x);
}

#define D_MODEL 1024
#define SEQ     2048
#define NHEAD   16
// 1/sqrt(HEAD) * log2(e): folded into Wq/bq so QK^T scores are in exp2 domain
#define QSC     0.1803368801f
#define MBIAS   (-1.4426950408e9f)   // -1e9 * log2(e)

// ---------- pre: fp32->bf16 conversions needed BY qkv (x,y,Wq,Wk,Wv) --------
// mask scan and Wo conversion live in qkv_kernel's grid (dep-free filler).
__global__ __launch_bounds__(256) void pre_kernel(
    const float* __restrict__ x,  const float* __restrict__ y,
    const float* __restrict__ wq, const float* __restrict__ wk,
    const float* __restrict__ wv,
    u16* __restrict__ xb, u16* __restrict__ yb,
    u16* __restrict__ wqb, u16* __restrict__ wkb,
    u16* __restrict__ wvb) {
  const int bid = blockIdx.x;
  const float* src;
  u16* dst;
  int base;
  float sA = 1.0f;                   // out = f2bf(v*sA)
  if (bid < 2048)      { src = x;    dst = xb;    base = 0; }
  else if (bid < 4096) { src = y;    dst = yb;    base = 2048; }
  else if (bid < 4608) { src = wq;   dst = wqb;   base = 4096; sA = QSC; }
  else if (bid < 5120) { src = wk;   dst = wkb;   base = 4608; }
  else                 { src = wv;   dst = wvb;   base = 5120; }
  const int i = (((bid - base) * 256) + threadIdx.x) * 8;
  const float4 a = *(const float4*)(src + i);
  const float4 b = *(const float4*)(src + i + 4);
  ushort4 lo, hi;
  lo.x = f2bf(a.x * sA); lo.y = f2bf(a.y * sA);
  lo.z = f2bf(a.z * sA); lo.w = f2bf(a.w * sA);
  hi.x = f2bf(b.x * sA); hi.y = f2bf(b.y * sA);
  hi.z = f2bf(b.z * sA); hi.w = f2bf(b.w * sA);
  *(ushort4*)(dst + i) = lo;
  *(ushort4*)(dst + i + 4) = hi;
}

// ---------- 128x128 BK=64 gemm_bt block (D = A @ W^T + bias*bscale) ----------
// MODE 0: D bf16 row-major [M,1024]; MODE 1: D fp32 row-major;
// MODE 2: D = vt, bf16 transposed [(b*16+h)*64+d][s] via LDS transpose epilogue.
// S is the caller's 16384-u16 LDS buffer (kernel-scope: unions instantiations).
template <int MODE, typename OT>
__device__ __forceinline__ void gemm_block_128(u16* S,
                                               const u16* __restrict__ A,
                                               const u16* __restrict__ W,
                                               const float* __restrict__ bias,
                                               float bscale,
                                               OT* __restrict__ D,
                                               int mb, int nb) {
  u16* Asl = S;
  u16* Bsl = S + 8192;
  const int tid = threadIdx.x;
  const int w = tid >> 6, lane = tid & 63, quad = lane >> 4, l16 = lane & 15;
  const int wm = (w & 1) * 64, wn = (w >> 1) * 64;
  const int cidx = w * 64 + lane;

  f32x4 acc[4][4];
#pragma unroll
  for (int i = 0; i < 4; ++i)
#pragma unroll
    for (int j = 0; j < 4; ++j) acc[i][j] = f32x4{0.f, 0.f, 0.f, 0.f};

  for (int k0 = 0; k0 < 1024; k0 += 64) {
    __syncthreads();
#pragma unroll
    for (int t = 0; t < 4; ++t) {
      const int idx = t * 256 + cidx;          // 16B-chunk id, 0..1023
      const int row = idx >> 3;                // 8 chunks per 64-elem row
      const int g = (idx & 7) ^ (row & 7);     // swizzled source chunk
      const size_t dst = (size_t)(t * 4 + w) * 1024;
      gld_lds16(A + (size_t)(mb * 128 + row) * 1024 + k0 + g * 8, (char*)Asl + dst);
      gld_lds16(W + (size_t)(nb * 128 + row) * 1024 + k0 + g * 8, (char*)Bsl + dst);
    }
    __syncthreads();

#pragma unroll
    for (int kk = 0; kk < 2; ++kk) {
      bf16x8 af[4], bfr[4];
#pragma unroll
      for (int i = 0; i < 4; ++i) {
        const int ar = wm + i * 16 + l16;
        const int br = wn + i * 16 + l16;
        af[i]  = ld_frag(Asl + ar * 64 + (((kk * 4 + quad) ^ (ar & 7)) * 8));
        bfr[i] = ld_frag(Bsl + br * 64 + (((kk * 4 + quad) ^ (br & 7)) * 8));
      }
#pragma unroll
      for (int i = 0; i < 4; ++i)
#pragma unroll
        for (int j = 0; j < 4; ++j) acc[i][j] = mfma16(af[i], bfr[j], acc[i][j]);
    }
  }

  if constexpr (MODE == 2) {
    // transposed epilogue: acc tile [128 s][128 d] -> LDS [d][s] -> vt rows
    __syncthreads();   // all waves done with Asl/Bsl frag reads
#pragma unroll
    for (int i = 0; i < 4; ++i)
#pragma unroll
      for (int j = 0; j < 4; ++j) {
        const int dl = wn + j * 16 + l16;
        const float bv = bias[nb * 128 + dl];
        const int sx = (wm + i * 16 + quad * 4) ^ ((dl & 15) << 3);
        uint2 pv;
        pv.x = (u32)f2bf(acc[i][j][0] + bv) | ((u32)f2bf(acc[i][j][1] + bv) << 16);
        pv.y = (u32)f2bf(acc[i][j][2] + bv) | ((u32)f2bf(acc[i][j][3] + bv) << 16);
        *(uint2*)(S + dl * 128 + sx) = pv;
      }
    __syncthreads();
    const int dl = tid >> 1, half = tid & 1;
    const int bb = mb >> 4, s0 = (mb & 15) * 128;
    u16* vrow = (u16*)D + (size_t)(bb * 1024 + nb * 128 + dl) * SEQ + s0 + half * 64;
#pragma unroll
    for (int c = 0; c < 8; ++c) {
      const int pc = (half * 8 + c) ^ (dl & 15);
      *(uint4*)(vrow + c * 8) = *(const uint4*)(S + dl * 128 + pc * 8);
    }
  } else {
    // epilogue: C/D layout col=lane&15, row=quad*4+r  [verified m89/m91]
#pragma unroll
    for (int i = 0; i < 4; ++i)
#pragma unroll
      for (int j = 0; j < 4; ++j) {
        const int gn = nb * 128 + wn + j * 16 + l16;
        const float bv = bias[gn] * bscale;
#pragma unroll
        for (int r = 0; r < 4; ++r) {
          const int gm = mb * 128 + wm + i * 16 + quad * 4 + r;
          const float v = acc[i][j][r] + bv;
          if constexpr (sizeof(OT) == 2)
            D[(size_t)gm * 1024 + gn] = (OT)f2bf(v);
          else
            D[(size_t)gm * 1024 + gn] = (OT)v;
        }
      }
  }
}

// ---------- 128x64 BK=64 gemm_bt block, fp32 out (for oproj) ----------
__device__ __forceinline__ void gemm_block_n64(const u16* __restrict__ A,
                                               const u16* __restrict__ W,
                                               const float* __restrict__ bias,
                                               float* __restrict__ D,
                                               int mb, int nb) {
  __shared__ __align__(16) u16 S[12288];     // Asl 8192 u16 + Bsl 4096 u16
  u16* Asl = S;
  u16* Bsl = S + 8192;
  const int tid = threadIdx.x;
  const int w = tid >> 6, lane = tid & 63, quad = lane >> 4, l16 = lane & 15;
  const int wm = w * 32;
  const int cidx = w * 64 + lane;

  f32x4 acc[2][4];
#pragma unroll
  for (int i = 0; i < 2; ++i)
#pragma unroll
    for (int j = 0; j < 4; ++j) acc[i][j] = f32x4{0.f, 0.f, 0.f, 0.f};

  for (int k0 = 0; k0 < 1024; k0 += 64) {
    __syncthreads();
#pragma unroll
    for (int t = 0; t < 4; ++t) {              // A: 128 rows x 64 cols
      const int idx = t * 256 + cidx;
      const int row = idx >> 3;
      const int g = (idx & 7) ^ (row & 7);
      gld_lds16(A + (size_t)(mb * 128 + row) * 1024 + k0 + g * 8,
                (char*)Asl + (size_t)(t * 4 + w) * 1024);
    }
#pragma unroll
    for (int t = 0; t < 2; ++t) {              // B: 64 rows x 64 cols
      const int idx = t * 256 + cidx;
      const int row = idx >> 3;
      const int g = (idx & 7) ^ (row & 7);
      gld_lds16(W + (size_t)(nb * 64 + row) * 1024 + k0 + g * 8,
                (char*)Bsl + (size_t)(t * 4 + w) * 1024);
    }
    __syncthreads();

#pragma unroll
    for (int kk = 0; kk < 2; ++kk) {
      bf16x8 af[2], bfr[4];
#pragma unroll
      for (int i = 0; i < 2; ++i) {
        const int ar = wm + i * 16 + l16;
        af[i] = ld_frag(Asl + ar * 64 + (((kk * 4 + quad) ^ (ar & 7)) * 8));
      }
#pragma unroll
      for (int j = 0; j < 4; ++j) {
        const int br = j * 16 + l16;
        bfr[j] = ld_frag(Bsl + br * 64 + (((kk * 4 + quad) ^ (br & 7)) * 8));
      }
#pragma unroll
      for (int i = 0; i < 2; ++i)
#pragma unroll
        for (int j = 0; j < 4; ++j) acc[i][j] = mfma16(af[i], bfr[j], acc[i][j]);
    }
  }

#pragma unroll
  for (int i = 0; i < 2; ++i)
#pragma unroll
    for (int j = 0; j < 4; ++j) {
      const int gn = nb * 64 + j * 16 + l16;
      const float bv = bias[gn];
#pragma unroll
      for (int r = 0; r < 4; ++r) {
        const int gm = mb * 128 + wm + i * 16 + quad * 4 + r;
        D[(size_t)gm * 1024 + gn] = acc[i][j][r] + bv;
      }
    }
}

// ---------- qkv (+ fused mask scan & Wo conversion as filler blocks) --------
__global__ __launch_bounds__(256) void qkv_kernel(
    const u16* __restrict__ xb, const u16* __restrict__ yb,
    const u16* __restrict__ Wqb, const u16* __restrict__ Wkb, const u16* __restrict__ Wvb,
    const float* __restrict__ bq, const float* __restrict__ bk, const float* __restrict__ bv,
    const float* __restrict__ mask, const float* __restrict__ wo,
    u16* __restrict__ qb, u16* __restrict__ kb, u16* __restrict__ vt,
    u16* __restrict__ wob, u32* __restrict__ flags) {
  __shared__ __align__(16) u16 S[16384];     // one 32 KB buffer for ALL modes
  const int by = blockIdx.y;
  if (by < 4) {
    const int mx = by * 32 + blockIdx.x;       // 0..127
    const int lane = threadIdx.x & 63, wv8 = threadIdx.x >> 6;
    for (int r = 0; r < 32; ++r) {
      const int row = mx * 32 + r;             // = b*2048 + q, 0..4095
      const size_t i = (size_t)row * SEQ + threadIdx.x * 8;
      const float4 a = *(const float4*)(mask + i);
      const float4 b = *(const float4*)(mask + i + 4);
      const bool m8 = (a.x != 1.f) || (a.y != 1.f) || (a.z != 1.f) || (a.w != 1.f) ||
                      (b.x != 1.f) || (b.y != 1.f) || (b.z != 1.f) || (b.w != 1.f);
      const unsigned long long bal = __ballot(m8);
      if (lane == 0) {
        u32 bits = 0;
#pragma unroll
        for (int g = 0; g < 8; ++g)
          bits |= (((bal >> (8 * g)) & 0xFFull) ? 1u : 0u) << g;
        if (bits) {
          const int bb = row >> 11, q = row & 2047;
          atomicOr(&flags[bb * 32 + (q >> 6)], bits << (wv8 * 8));
        }
      }
    }
    return;
  }
  if (by < 20) {
    const int wid = (by - 4) * 32 + blockIdx.x;          // 0..511
    const int i = (wid * 256 + threadIdx.x) * 8;
    const float4 a = *(const float4*)(wo + i);
    const float4 b = *(const float4*)(wo + i + 4);
    ushort4 lo, hi;
    lo.x = f2bf(a.x); lo.y = f2bf(a.y); lo.z = f2bf(a.z); lo.w = f2bf(a.w);
    hi.x = f2bf(b.x); hi.y = f2bf(b.y); hi.z = f2bf(b.z); hi.w = f2bf(b.w);
    *(ushort4*)(wob + i) = lo;
    *(ushort4*)(wob + i + 4) = hi;
    return;
  }
  const int mat = (by - 20) >> 3;
  const int nb = (by - 20) & 7;
  const int mb = blockIdx.x;
  if (mat == 0)      gemm_block_128<0, u16>(S, xb, Wqb, bq, QSC,  qb, mb, nb);
  else if (mat == 1) gemm_block_128<0, u16>(S, yb, Wkb, bk, 1.0f, kb, mb, nb);
  else               gemm_block_128<2, u16>(S, yb, Wvb, bv, 1.0f, vt, mb, nb);
}

__global__ __launch_bounds__(256) void oproj_kernel(
    const u16* __restrict__ ctx, const u16* __restrict__ Wob,
    const float* __restrict__ bo, float* __restrict__ out) {
  gemm_block_n64(ctx, Wob, bo, out, blockIdx.x, blockIdx.y);
}

// ---------- flash attention v9: 32-q blocks, 8 blocks/CU --------------------
// r7 post-mortem: per-iter pipe-busy sums to the wall (MFMA 26 + VALU 40 +
// DS ~15%) -> pipes run sequentially, latency-bound, and occupancy was
// GRID-capped (1024 blocks = 4/CU; LDS would allow 6). Fix: halve the block's
// q-range. Block = 32 q x 64 kv-tile; wave w = (qg=w&1, kg=w>>1) owns 16 q x
// one 32-kv half (v8's verified layout minus the qs-subtile). LDS: Ks 8K +
// Vs 8K + Ps[32][64] 4K = 20 KB -> 8 blocks/CU; grid 2048 = exactly 8/CU ->
// 32 waves/CU (100%). VGPR pinned <=64 via __launch_bounds__(256,8).
// K/V staged 2x more often (L2 absorbs; HBM FETCH ~12 MB unchanged).
// Cross-kg O/l reduction through LDS at the end (v8 machinery).
__global__ __launch_bounds__(256, 8) void attn_kernel(
    const u16* __restrict__ qb, const u16* __restrict__ kb,
    const u16* __restrict__ vt, const float* __restrict__ mask,
    const u32* __restrict__ flags, u16* __restrict__ ctx) {
  const int h = blockIdx.x;
  const int qblk = blockIdx.y;   // 0..63, 32 q each
  const int b = blockIdx.z;
  const int tid = threadIdx.x, w = tid >> 6, lane = tid & 63;
  const int quad = lane >> 4, l16 = lane & 15;
  const int qg = w & 1, kg = w >> 1;
  const int q0 = qblk * 32;

  __shared__ __align__(16) u16 Ks[64 * 64];   // [kv][d] swizzled rows, 8 KB
  __shared__ __align__(16) u16 Vs[64 * 64];   // [d][kv] swizzled rows, 8 KB
  __shared__ __align__(16) u16 Ps[32 * 64];   // P [q][kv] swizzled, 4 KB

  const u32 fl = flags[(b << 5) + (qblk >> 1)];  // block-uniform mask bits

  // Q fragments: 16 q-rows per wave, d split in halves by quad
  const int qrow = qg * 16 + l16;
  const u16* qp = qb + (size_t)(b * SEQ + q0 + qrow) * D_MODEL + h * 64;
  const bf16x8 qf0 = ld_frag(qp + quad * 8);
  const bf16x8 qf1 = ld_frag(qp + 32 + quad * 8);

  // ones B-frag: row n==0 all 1.0 -> lane l16==0 holds ones
  bf16x8 onesf;
  {
    u16x8 t;
    const u16 ov = (l16 == 0) ? (u16)0x3F80 : (u16)0;
#pragma unroll
    for (int j = 0; j < 8; ++j) t[j] = ov;
    onesf = __builtin_bit_cast(bf16x8, t);
  }

  f32x4 O[4];   // [d-tile]; lane: q=quad*4+r, d=dt*16+l16
#pragma unroll
  for (int dt = 0; dt < 4; ++dt) O[dt] = f32x4{0.f, 0.f, 0.f, 0.f};
  f32x4 L = f32x4{0.f, 0.f, 0.f, 0.f};

  const int cidx = w * 64 + lane;
  const int bhalf = (quad & 1) * 4;           // b64 half-chunk offset (u16)

  // hoisted loop-invariant LDS fragment pointers
  const u16 *kf0p[2], *kf1p[2], *vfp[4], *pfp;
  u16* psp[2];
#pragma unroll
  for (int nt = 0; nt < 2; ++nt) {
    const int kvl = kg * 32 + nt * 16 + l16;
    kf0p[nt] = Ks + kvl * 64 + ((quad ^ (kvl & 7)) * 8);
    kf1p[nt] = Ks + kvl * 64 + (((4 + quad) ^ (kvl & 7)) * 8);
  }
#pragma unroll
  for (int dt = 0; dt < 4; ++dt) {
    const int vr = dt * 16 + l16;
    vfp[dt] = Vs + vr * 64 + ((((kg * 4) + quad) ^ (vr & 7)) * 8);
  }
  {
    const int prow = qg * 16 + l16;
    pfp = Ps + prow * 64 + ((((kg * 4) + quad) ^ (prow & 7)) * 8);
#pragma unroll
    for (int nt = 0; nt < 2; ++nt) {
      const int ck = kg * 4 + nt * 2 + (quad >> 1);
      psp[nt] = Ps + prow * 64 + ((ck ^ (prow & 7)) * 8) + bhalf;
    }
  }

  // loop-carried staging pointers (t=0 and t=1 chunk of each stream)
  const int r0 = cidx >> 3,        g0 = (cidx & 7) ^ (r0 & 7);
  const int r1 = (256 + cidx) >> 3, g1 = ((256 + cidx) & 7) ^ (r1 & 7);
  const u16* kp0 = kb + (size_t)(b * SEQ + r0) * D_MODEL + h * 64 + g0 * 8;
  const u16* kp1 = kb + (size_t)(b * SEQ + r1) * D_MODEL + h * 64 + g1 * 8;
  const u16* vp0 = vt + ((size_t)((b * NHEAD + h) * 64 + r0)) * SEQ + g0 * 8;
  const u16* vp1 = vt + ((size_t)((b * NHEAD + h) * 64 + r1)) * SEQ + g1 * 8;
  // slow-path mask pointer: 4 consecutive f32 at the lane's (q, kv) position
  const float* mp = mask + (size_t)(b * SEQ + q0 + qrow) * SEQ + kg * 32 + quad * 4;
  const size_t dst0 = (size_t)w * 1024;
  const size_t dst1 = (size_t)(4 + w) * 1024;

  for (int kt = 0; kt < 32; ++kt) {
    const bool doBias = (fl >> kt) & 1u;      // block-uniform branch
    __syncthreads();   // prior iteration's LDS reads complete
    gld_lds16(kp0, (char*)Ks + dst0);
    gld_lds16(kp1, (char*)Ks + dst1);
    gld_lds16(vp0, (char*)Vs + dst0);
    gld_lds16(vp1, (char*)Vs + dst1);
    kp0 += 64 * D_MODEL; kp1 += 64 * D_MODEL;   // next 64 kv rows
    vp0 += 64;           vp1 += 64;             // next 64 kv cols
    __syncthreads();

    // S^T = K Q^T for this wave's (qg, kg): z[nt]
    f32x4 z[2];
    __builtin_amdgcn_s_setprio(1);
#pragma unroll
    for (int nt = 0; nt < 2; ++nt) {
      const bf16x8 kf0 = ld_frag(kf0p[nt]);
      const bf16x8 kf1 = ld_frag(kf1p[nt]);
      f32x4 zz;
      if (doBias) {
        const float4 mv = *(const float4*)(mp + nt * 16);
        zz[0] = (1.f - mv.x) * MBIAS;
        zz[1] = (1.f - mv.y) * MBIAS;
        zz[2] = (1.f - mv.z) * MBIAS;
        zz[3] = (1.f - mv.w) * MBIAS;
      } else {
        zz = f32x4{0.f, 0.f, 0.f, 0.f};
      }
      zz = mfma16(kf0, qf0, zz);
      zz = mfma16(kf1, qf1, zz);
      z[nt] = zz;
    }
    __builtin_amdgcn_s_setprio(0);
    mp += 64;

    // p = 2^S -> bf16, store into this wave's private P block
#pragma unroll
    for (int nt = 0; nt < 2; ++nt) {
      uint2 pv;
      pv.x = pack_rnd(ex2(z[nt][0]), ex2(z[nt][1]));
      pv.y = pack_rnd(ex2(z[nt][2]), ex2(z[nt][3]));
      *(uint2*)psp[nt] = pv;
    }

    // P A-frag (wave-private), then O += P V ; l += P * ones
    const bf16x8 pf = ld_frag(pfp);
    __builtin_amdgcn_s_setprio(1);
#pragma unroll
    for (int dt = 0; dt < 4; ++dt) {
      const bf16x8 vf = ld_frag(vfp[dt]);
      O[dt] = mfma16(pf, vf, O[dt]);
    }
    L = mfma16(pf, onesf, L);
    __builtin_amdgcn_s_setprio(0);
  }

  // ---- cross-kg reduction: O_full = O(kg=0) + O(kg=1), same for l ----
  __syncthreads();   // all waves done with Ks/Vs/Ps tile reads
  if (kg == 1) {
    float* Of = (float*)(qg ? Vs : Ks);      // 4 KB per q-group
    float* Lf = (float*)Ps + qg * 256;
#pragma unroll
    for (int dt = 0; dt < 4; ++dt)
      *(f32x4*)(Of + dt * 256 + lane * 4) = O[dt];
    *(f32x4*)(Lf + lane * 4) = L;
  }
  __syncthreads();
  if (kg == 0) {
    const float* Of = (const float*)(qg ? Vs : Ks);
    const float* Lf = (const float*)Ps + qg * 256;
#pragma unroll
    for (int dt = 0; dt < 4; ++dt)
      O[dt] += *(const f32x4*)(Of + dt * 256 + lane * 4);
    L += *(const f32x4*)(Lf + lane * 4);

    // l in col-0 lanes of each quad; ctx[b,q,h*64+d] = O / l
    float inv[4];
#pragma unroll
    for (int r = 0; r < 4; ++r)
      inv[r] = 1.0f / __shfl(L[r], lane & 48, 64);

#pragma unroll
    for (int dt = 0; dt < 4; ++dt)
#pragma unroll
      for (int r = 0; r < 4; ++r) {
        const int gq = b * SEQ + q0 + qg * 16 + quad * 4 + r;
        const int gd = h * 64 + dt * 16 + l16;
        ctx[(size_t)gq * D_MODEL + gd] = f2bf(O[dt][r] * inv[r]);
      }
  }
}

// ---------- host ----------
extern "C" void kernel_launch(void* const* d_in, const int* in_sizes, int n_in,
                              void* d_out, int out_size, void* d_ws, size_t ws_size,
                              hipStream_t stream) {
  (void)in_sizes; (void)n_in; (void)out_size; (void)ws_size;
  const float* x    = (const float*)d_in[0];
  const float* y    = (const float*)d_in[1];
  const float* mask = (const float*)d_in[2];
  const float* Wq   = (const float*)d_in[3];
  const float* bq   = (const float*)d_in[4];
  const float* Wk   = (const float*)d_in[5];
  const float* bk   = (const float*)d_in[6];
  const float* Wv   = (const float*)d_in[7];
  const float* bv   = (const float*)d_in[8];
  const float* Wo   = (const float*)d_in[9];
  const float* bo   = (const float*)d_in[10];
  float* out = (float*)d_out;

  // 56 MB + 256 B workspace, aliased by lifetime. attn's slow path reads
  // mask f32 directly; d_out is written only by oproj.
  const size_t M4 = (size_t)4096 * 1024;   // 4M u16 = 8 MB
  const size_t M1 = (size_t)1024 * 1024;   // 1M u16 = 2 MB
  u16* qbuf  = (u16*)d_ws;         // [0,8)   qkv -> attn
  u16* kbuf  = qbuf + M4;          // [8,16)  qkv -> attn
  u16* vt    = kbuf + M4;          // [16,24) qkv (transposed) -> attn
  u16* cbuf  = vt + M4;            // [24,32) attn -> oproj
  u16* wob   = cbuf + M4;          // [32,34) qkv(filler) -> oproj
  u16* xb    = wob + M1;           // [34,42) pre -> qkv
  u16* yb    = xb + M4;            // [42,50) pre -> qkv
  u16* wqb   = yb + M4;            // [50,52) pre -> qkv
  u16* wkb   = wqb + M1;           // [52,54)
  u16* wvb   = wkb + M1;           // [54,56)
  u32* flags = (u32*)(wvb + M1);   // [56MB, +256B) mask-tile bits -> attn

  hipMemsetAsync(flags, 0, 64 * sizeof(u32), stream);
  pre_kernel<<<dim3(5632, 1, 1), 256, 0, stream>>>(
      x, y, Wq, Wk, Wv, xb, yb, wqb, wkb, wvb);
  qkv_kernel<<<dim3(32, 44, 1), 256, 0, stream>>>(xb, yb, wqb, wkb, wvb,
                                                  bq, bk, bv, mask, Wo,
                                                  qbuf, kbuf, vt, wob, flags);
  attn_kernel<<<dim3(NHEAD, 64, 2), 256, 0, stream>>>(qbuf, kbuf, vt, mask, flags, cbuf);
  oproj_kernel<<<dim3(32, 16, 1), 256, 0, stream>>>(cbuf, wob, bo, out);
}

// Round 9
// 237.022 us; speedup vs baseline: 1.1074x; 1.1074x over previous
//
#include <hip/hip_runtime.h>
#include <cstdint>
#include <cstddef>

// ---------- types & helpers ----------
typedef __bf16 bf16x8 __attribute__((ext_vector_type(8)));
typedef float f32x4 __attribute__((ext_vector_type(4)));
typedef unsigned short u16;
typedef unsigned short u16x8 __attribute__((ext_vector_type(8)));
typedef unsigned int u32;

typedef __attribute__((address_space(1))) void gvoid_t;
typedef __attribute__((address_space(3))) void lvoid_t;

// async global->LDS, 16B per lane. LDS dest = wave-uniform base + lane*16.
__device__ __forceinline__ void gld_lds16(const void* g, void* l) {
  __builtin_amdgcn_global_load_lds((gvoid_t*)g, (lvoid_t*)l, 16, 0, 0);
}

__device__ __forceinline__ u16 f2bf(float f) {
  u32 u = __float_as_uint(f);
  u += 0x7fffu + ((u >> 16) & 1u);   // RNE
  return (u16)(u >> 16);
}
// packed f32x2 -> bf16x2 via v_perm_b32, half-up rounding: 3 VALU ops total
__device__ __forceinline__ u32 pack_rnd(float a, float b) {
  const u32 ua = __float_as_uint(a) + 0x8000u;
  const u32 ub = __float_as_uint(b) + 0x8000u;
  return __builtin_amdgcn_perm(ub, ua, 0x07060302u);  // [ub.hi16 : ua.hi16]
}
__device__ __forceinline__ bf16x8 ld_frag(const u16* p) {
  return __builtin_bit_cast(bf16x8, *(const uint4*)p);
}
__device__ __forceinline__ f32x4 mfma16(bf16x8 a, bf16x8 b, f32x4 c) {
  return __builtin_amdgcn_mfma_f32_16x16x32_bf16(a, b, c, 0, 0, 0);
}
// 2^x via v_exp_f32 (single instruction)
__device__ __forceinline__ float ex2(float x) {
  return __builtin_amdgcn_exp2f(x);
}

#define D_MODEL 1024
#define SEQ     2048
#define NHEAD   16
// 1/sqrt(HEAD) * log2(e): folded into Wq/bq so QK^T scores are in exp2 domain
#define QSC     0.1803368801f
#define MBIAS   (-1.4426950408e9f)   // -1e9 * log2(e)

// ---------- pre: fp32->bf16 conversions needed BY qkv (x,y,Wq,Wk,Wv) --------
// mask scan and Wo conversion live in qkv_kernel's grid (dep-free filler).
__global__ __launch_bounds__(256) void pre_kernel(
    const float* __restrict__ x,  const float* __restrict__ y,
    const float* __restrict__ wq, const float* __restrict__ wk,
    const float* __restrict__ wv,
    u16* __restrict__ xb, u16* __restrict__ yb,
    u16* __restrict__ wqb, u16* __restrict__ wkb,
    u16* __restrict__ wvb) {
  const int bid = blockIdx.x;
  const float* src;
  u16* dst;
  int base;
  float sA = 1.0f;                   // out = f2bf(v*sA)
  if (bid < 2048)      { src = x;    dst = xb;    base = 0; }
  else if (bid < 4096) { src = y;    dst = yb;    base = 2048; }
  else if (bid < 4608) { src = wq;   dst = wqb;   base = 4096; sA = QSC; }
  else if (bid < 5120) { src = wk;   dst = wkb;   base = 4608; }
  else                 { src = wv;   dst = wvb;   base = 5120; }
  const int i = (((bid - base) * 256) + threadIdx.x) * 8;
  const float4 a = *(const float4*)(src + i);
  const float4 b = *(const float4*)(src + i + 4);
  ushort4 lo, hi;
  lo.x = f2bf(a.x * sA); lo.y = f2bf(a.y * sA);
  lo.z = f2bf(a.z * sA); lo.w = f2bf(a.w * sA);
  hi.x = f2bf(b.x * sA); hi.y = f2bf(b.y * sA);
  hi.z = f2bf(b.z * sA); hi.w = f2bf(b.w * sA);
  *(ushort4*)(dst + i) = lo;
  *(ushort4*)(dst + i + 4) = hi;
}

// ---------- 128x128 BK=64 gemm_bt block (D = A @ W^T + bias*bscale) ----------
// MODE 0: D bf16 row-major [M,1024]; MODE 1: D fp32 row-major;
// MODE 2: D = vt, bf16 transposed [(b*16+h)*64+d][s] via LDS transpose epilogue.
// S is the caller's 16384-u16 LDS buffer (kernel-scope: unions instantiations).
template <int MODE, typename OT>
__device__ __forceinline__ void gemm_block_128(u16* S,
                                               const u16* __restrict__ A,
                                               const u16* __restrict__ W,
                                               const float* __restrict__ bias,
                                               float bscale,
                                               OT* __restrict__ D,
                                               int mb, int nb) {
  u16* Asl = S;
  u16* Bsl = S + 8192;
  const int tid = threadIdx.x;
  const int w = tid >> 6, lane = tid & 63, quad = lane >> 4, l16 = lane & 15;
  const int wm = (w & 1) * 64, wn = (w >> 1) * 64;
  const int cidx = w * 64 + lane;

  f32x4 acc[4][4];
#pragma unroll
  for (int i = 0; i < 4; ++i)
#pragma unroll
    for (int j = 0; j < 4; ++j) acc[i][j] = f32x4{0.f, 0.f, 0.f, 0.f};

  for (int k0 = 0; k0 < 1024; k0 += 64) {
    __syncthreads();
#pragma unroll
    for (int t = 0; t < 4; ++t) {
      const int idx = t * 256 + cidx;          // 16B-chunk id, 0..1023
      const int row = idx >> 3;                // 8 chunks per 64-elem row
      const int g = (idx & 7) ^ (row & 7);     // swizzled source chunk
      const size_t dst = (size_t)(t * 4 + w) * 1024;
      gld_lds16(A + (size_t)(mb * 128 + row) * 1024 + k0 + g * 8, (char*)Asl + dst);
      gld_lds16(W + (size_t)(nb * 128 + row) * 1024 + k0 + g * 8, (char*)Bsl + dst);
    }
    __syncthreads();

#pragma unroll
    for (int kk = 0; kk < 2; ++kk) {
      bf16x8 af[4], bfr[4];
#pragma unroll
      for (int i = 0; i < 4; ++i) {
        const int ar = wm + i * 16 + l16;
        const int br = wn + i * 16 + l16;
        af[i]  = ld_frag(Asl + ar * 64 + (((kk * 4 + quad) ^ (ar & 7)) * 8));
        bfr[i] = ld_frag(Bsl + br * 64 + (((kk * 4 + quad) ^ (br & 7)) * 8));
      }
#pragma unroll
      for (int i = 0; i < 4; ++i)
#pragma unroll
        for (int j = 0; j < 4; ++j) acc[i][j] = mfma16(af[i], bfr[j], acc[i][j]);
    }
  }

  if constexpr (MODE == 2) {
    // transposed epilogue: acc tile [128 s][128 d] -> LDS [d][s] -> vt rows
    __syncthreads();   // all waves done with Asl/Bsl frag reads
#pragma unroll
    for (int i = 0; i < 4; ++i)
#pragma unroll
      for (int j = 0; j < 4; ++j) {
        const int dl = wn + j * 16 + l16;
        const float bv = bias[nb * 128 + dl];
        const int sx = (wm + i * 16 + quad * 4) ^ ((dl & 15) << 3);
        uint2 pv;
        pv.x = (u32)f2bf(acc[i][j][0] + bv) | ((u32)f2bf(acc[i][j][1] + bv) << 16);
        pv.y = (u32)f2bf(acc[i][j][2] + bv) | ((u32)f2bf(acc[i][j][3] + bv) << 16);
        *(uint2*)(S + dl * 128 + sx) = pv;
      }
    __syncthreads();
    const int dl = tid >> 1, half = tid & 1;
    const int bb = mb >> 4, s0 = (mb & 15) * 128;
    u16* vrow = (u16*)D + (size_t)(bb * 1024 + nb * 128 + dl) * SEQ + s0 + half * 64;
#pragma unroll
    for (int c = 0; c < 8; ++c) {
      const int pc = (half * 8 + c) ^ (dl & 15);
      *(uint4*)(vrow + c * 8) = *(const uint4*)(S + dl * 128 + pc * 8);
    }
  } else {
    // epilogue: C/D layout col=lane&15, row=quad*4+r  [verified m89/m91]
#pragma unroll
    for (int i = 0; i < 4; ++i)
#pragma unroll
      for (int j = 0; j < 4; ++j) {
        const int gn = nb * 128 + wn + j * 16 + l16;
        const float bv = bias[gn] * bscale;
#pragma unroll
        for (int r = 0; r < 4; ++r) {
          const int gm = mb * 128 + wm + i * 16 + quad * 4 + r;
          const float v = acc[i][j][r] + bv;
          if constexpr (sizeof(OT) == 2)
            D[(size_t)gm * 1024 + gn] = (OT)f2bf(v);
          else
            D[(size_t)gm * 1024 + gn] = (OT)v;
        }
      }
  }
}

// ---------- 128x64 BK=64 gemm_bt block, fp32 out (for oproj) ----------
__device__ __forceinline__ void gemm_block_n64(const u16* __restrict__ A,
                                               const u16* __restrict__ W,
                                               const float* __restrict__ bias,
                                               float* __restrict__ D,
                                               int mb, int nb) {
  __shared__ __align__(16) u16 S[12288];     // Asl 8192 u16 + Bsl 4096 u16
  u16* Asl = S;
  u16* Bsl = S + 8192;
  const int tid = threadIdx.x;
  const int w = tid >> 6, lane = tid & 63, quad = lane >> 4, l16 = lane & 15;
  const int wm = w * 32;
  const int cidx = w * 64 + lane;

  f32x4 acc[2][4];
#pragma unroll
  for (int i = 0; i < 2; ++i)
#pragma unroll
    for (int j = 0; j < 4; ++j) acc[i][j] = f32x4{0.f, 0.f, 0.f, 0.f};

  for (int k0 = 0; k0 < 1024; k0 += 64) {
    __syncthreads();
#pragma unroll
    for (int t = 0; t < 4; ++t) {              // A: 128 rows x 64 cols
      const int idx = t * 256 + cidx;
      const int row = idx >> 3;
      const int g = (idx & 7) ^ (row & 7);
      gld_lds16(A + (size_t)(mb * 128 + row) * 1024 + k0 + g * 8,
                (char*)Asl + (size_t)(t * 4 + w) * 1024);
    }
#pragma unroll
    for (int t = 0; t < 2; ++t) {              // B: 64 rows x 64 cols
      const int idx = t * 256 + cidx;
      const int row = idx >> 3;
      const int g = (idx & 7) ^ (row & 7);
      gld_lds16(W + (size_t)(nb * 64 + row) * 1024 + k0 + g * 8,
                (char*)Bsl + (size_t)(t * 4 + w) * 1024);
    }
    __syncthreads();

#pragma unroll
    for (int kk = 0; kk < 2; ++kk) {
      bf16x8 af[2], bfr[4];
#pragma unroll
      for (int i = 0; i < 2; ++i) {
        const int ar = wm + i * 16 + l16;
        af[i] = ld_frag(Asl + ar * 64 + (((kk * 4 + quad) ^ (ar & 7)) * 8));
      }
#pragma unroll
      for (int j = 0; j < 4; ++j) {
        const int br = j * 16 + l16;
        bfr[j] = ld_frag(Bsl + br * 64 + (((kk * 4 + quad) ^ (br & 7)) * 8));
      }
#pragma unroll
      for (int i = 0; i < 2; ++i)
#pragma unroll
        for (int j = 0; j < 4; ++j) acc[i][j] = mfma16(af[i], bfr[j], acc[i][j]);
    }
  }

#pragma unroll
  for (int i = 0; i < 2; ++i)
#pragma unroll
    for (int j = 0; j < 4; ++j) {
      const int gn = nb * 64 + j * 16 + l16;
      const float bv = bias[gn];
#pragma unroll
      for (int r = 0; r < 4; ++r) {
        const int gm = mb * 128 + wm + i * 16 + quad * 4 + r;
        D[(size_t)gm * 1024 + gn] = acc[i][j][r] + bv;
      }
    }
}

// ---------- qkv (+ fused mask scan & Wo conversion as filler blocks) --------
__global__ __launch_bounds__(256) void qkv_kernel(
    const u16* __restrict__ xb, const u16* __restrict__ yb,
    const u16* __restrict__ Wqb, const u16* __restrict__ Wkb, const u16* __restrict__ Wvb,
    const float* __restrict__ bq, const float* __restrict__ bk, const float* __restrict__ bv,
    const float* __restrict__ mask, const float* __restrict__ wo,
    u16* __restrict__ qb, u16* __restrict__ kb, u16* __restrict__ vt,
    u16* __restrict__ wob, u32* __restrict__ flags) {
  __shared__ __align__(16) u16 S[16384];     // one 32 KB buffer for ALL modes
  const int by = blockIdx.y;
  if (by < 4) {
    const int mx = by * 32 + blockIdx.x;       // 0..127
    const int lane = threadIdx.x & 63, wv8 = threadIdx.x >> 6;
    for (int r = 0; r < 32; ++r) {
      const int row = mx * 32 + r;             // = b*2048 + q, 0..4095
      const size_t i = (size_t)row * SEQ + threadIdx.x * 8;
      const float4 a = *(const float4*)(mask + i);
      const float4 b = *(const float4*)(mask + i + 4);
      const bool m8 = (a.x != 1.f) || (a.y != 1.f) || (a.z != 1.f) || (a.w != 1.f) ||
                      (b.x != 1.f) || (b.y != 1.f) || (b.z != 1.f) || (b.w != 1.f);
      const unsigned long long bal = __ballot(m8);
      if (lane == 0) {
        u32 bits = 0;
#pragma unroll
        for (int g = 0; g < 8; ++g)
          bits |= (((bal >> (8 * g)) & 0xFFull) ? 1u : 0u) << g;
        if (bits) {
          const int bb = row >> 11, q = row & 2047;
          atomicOr(&flags[bb * 32 + (q >> 6)], bits << (wv8 * 8));
        }
      }
    }
    return;
  }
  if (by < 20) {
    const int wid = (by - 4) * 32 + blockIdx.x;          // 0..511
    const int i = (wid * 256 + threadIdx.x) * 8;
    const float4 a = *(const float4*)(wo + i);
    const float4 b = *(const float4*)(wo + i + 4);
    ushort4 lo, hi;
    lo.x = f2bf(a.x); lo.y = f2bf(a.y); lo.z = f2bf(a.z); lo.w = f2bf(a.w);
    hi.x = f2bf(b.x); hi.y = f2bf(b.y); hi.z = f2bf(b.z); hi.w = f2bf(b.w);
    *(ushort4*)(wob + i) = lo;
    *(ushort4*)(wob + i + 4) = hi;
    return;
  }
  const int mat = (by - 20) >> 3;
  const int nb = (by - 20) & 7;
  const int mb = blockIdx.x;
  if (mat == 0)      gemm_block_128<0, u16>(S, xb, Wqb, bq, QSC,  qb, mb, nb);
  else if (mat == 1) gemm_block_128<0, u16>(S, yb, Wkb, bk, 1.0f, kb, mb, nb);
  else               gemm_block_128<2, u16>(S, yb, Wvb, bv, 1.0f, vt, mb, nb);
}

__global__ __launch_bounds__(256) void oproj_kernel(
    const u16* __restrict__ ctx, const u16* __restrict__ Wob,
    const float* __restrict__ bo, float* __restrict__ out) {
  gemm_block_n64(ctx, Wob, bo, out, blockIdx.x, blockIdx.y);
}

// ---------- flash attention v10: r6 winner + KVBLK=128 paired sub-tiles -----
// Revert of v9 (launch_bounds(256,8) -> 32 VGPR -> scratch spill: WRITE_SIZE
// 8->28.7 MB). Back to 64-q blocks, 4 waves x 16 q-rows, launch_bounds(256,4).
// Structural edit vs r6: stage BOTH 64-kv halves of a 128-kv stripe per outer
// iteration (Ks[2]/Vs[2], 40 KB LDS, still 4 blocks/CU), compute each half
// with the byte-identical r6 inner body (+half*4096 folds into the ds_read
// 16-bit offset). Barriers: 64 -> 32; vmcnt(0) drains: 32 -> 16. Ps (8 KB) is
// reused across halves: rows are wave-private, same-wave DS ordering suffices.
__global__ __launch_bounds__(256, 4) void attn_kernel(
    const u16* __restrict__ qb, const u16* __restrict__ kb,
    const u16* __restrict__ vt, const float* __restrict__ mask,
    const u32* __restrict__ flags, u16* __restrict__ ctx) {
  const int h = blockIdx.x;
  const int qblk = blockIdx.y;   // 0..31, 64 q each
  const int b = blockIdx.z;
  const int tid = threadIdx.x, w = tid >> 6, lane = tid & 63;
  const int quad = lane >> 4, l16 = lane & 15;
  const int q0 = qblk * 64;

  __shared__ __align__(16) u16 Ks[2][64 * 64];  // [kv][d] swizzled rows, 16 KB
  __shared__ __align__(16) u16 Vs[2][64 * 64];  // [d][kv] swizzled rows, 16 KB
  __shared__ __align__(16) u16 Ps[64 * 64];     // P [q][kv] swizzled, 8 KB

  const u32 fl = flags[(b << 5) + qblk];      // block-uniform mask-tile bits

  const int qrow = w * 16 + l16;              // q-local row (wave-private set)
  const u16* qp = qb + (size_t)(b * SEQ + q0 + qrow) * D_MODEL + h * 64;
  const bf16x8 qf0 = ld_frag(qp + quad * 8);
  const bf16x8 qf1 = ld_frag(qp + 32 + quad * 8);

  // ones B-frag: row n==0 all 1.0 -> lane l16==0 holds ones
  bf16x8 onesf;
  {
    u16x8 t;
    const u16 ov = (l16 == 0) ? (u16)0x3F80 : (u16)0;
#pragma unroll
    for (int j = 0; j < 8; ++j) t[j] = ov;
    onesf = __builtin_bit_cast(bf16x8, t);
  }

  f32x4 O[4];
#pragma unroll
  for (int dt = 0; dt < 4; ++dt) O[dt] = f32x4{0.f, 0.f, 0.f, 0.f};
  f32x4 O4 = f32x4{0.f, 0.f, 0.f, 0.f};

  const int cidx = w * 64 + lane;
  const int bhalf = (quad & 1) * 4;           // b64 half-chunk offset (u16)

  // hoisted loop-invariant LDS fragment pointers (based at half 0; half 1 is
  // +4096 u16 = +8192 B, folded into the ds_read immediate offset)
  const u16 *kf0p[4], *kf1p[4], *vf0p[4], *vf1p[4];
  u16* psp[4];
#pragma unroll
  for (int nt = 0; nt < 4; ++nt) {
    const int rl = nt * 16 + l16;
    kf0p[nt] = Ks[0] + rl * 64 + ((quad ^ (rl & 7)) * 8);
    kf1p[nt] = Ks[0] + rl * 64 + (((4 + quad) ^ (rl & 7)) * 8);
    vf0p[nt] = Vs[0] + rl * 64 + ((quad ^ (rl & 7)) * 8);
    vf1p[nt] = Vs[0] + rl * 64 + (((4 + quad) ^ (rl & 7)) * 8);
    const int ck = nt * 2 + (quad >> 1);
    psp[nt] = Ps + qrow * 64 + ((ck ^ (qrow & 7)) * 8) + bhalf;
  }
  const u16* pf0p = Ps + qrow * 64 + ((quad ^ (qrow & 7)) * 8);
  const u16* pf1p = Ps + qrow * 64 + (((4 + quad) ^ (qrow & 7)) * 8);

  // loop-carried staging pointers (t=0 and t=1 chunk of each stream)
  const int r0 = cidx >> 3,        g0 = (cidx & 7) ^ (r0 & 7);
  const int r1 = (256 + cidx) >> 3, g1 = ((256 + cidx) & 7) ^ (r1 & 7);
  const u16* kp0 = kb + (size_t)(b * SEQ + r0) * D_MODEL + h * 64 + g0 * 8;
  const u16* kp1 = kb + (size_t)(b * SEQ + r1) * D_MODEL + h * 64 + g1 * 8;
  const u16* vp0 = vt + ((size_t)((b * NHEAD + h) * 64 + r0)) * SEQ + g0 * 8;
  const u16* vp1 = vt + ((size_t)((b * NHEAD + h) * 64 + r1)) * SEQ + g1 * 8;
  // slow-path mask pointer: row q0+qrow, 4 consecutive f32 at col nt*16+quad*4
  const float* mp = mask + (size_t)(b * SEQ + q0 + qrow) * SEQ + quad * 4;
  const size_t dst0 = (size_t)w * 1024;
  const size_t dst1 = (size_t)(4 + w) * 1024;

  for (int kt = 0; kt < 16; ++kt) {            // 128 kv per outer iteration
    __syncthreads();   // prior stripe's LDS reads complete
#pragma unroll
    for (int hh = 0; hh < 2; ++hh) {
      gld_lds16(kp0, (char*)Ks[hh] + dst0);
      gld_lds16(kp1, (char*)Ks[hh] + dst1);
      gld_lds16(vp0, (char*)Vs[hh] + dst0);
      gld_lds16(vp1, (char*)Vs[hh] + dst1);
      kp0 += 64 * D_MODEL; kp1 += 64 * D_MODEL;   // next 64 kv rows
      vp0 += 64;           vp1 += 64;             // next 64 kv cols
    }
    __syncthreads();

#pragma unroll
    for (int hh = 0; hh < 2; ++hh) {
      const int ho = hh * 4096;                // u16 offset to half-1 buffers
      const bool doBias = (fl >> (kt * 2 + hh)) & 1u;   // block-uniform

      // S^T = K Q^T (+ mask bias on slow path; acc init in-register)
      f32x4 z[4];
      __builtin_amdgcn_s_setprio(1);
#pragma unroll
      for (int nt = 0; nt < 4; ++nt) {
        const bf16x8 kf0 = ld_frag(kf0p[nt] + ho);
        const bf16x8 kf1 = ld_frag(kf1p[nt] + ho);
        f32x4 zz;
        if (doBias) {
          const float4 mv = *(const float4*)(mp + nt * 16);
          zz[0] = (1.f - mv.x) * MBIAS;
          zz[1] = (1.f - mv.y) * MBIAS;
          zz[2] = (1.f - mv.z) * MBIAS;
          zz[3] = (1.f - mv.w) * MBIAS;
        } else {
          zz = f32x4{0.f, 0.f, 0.f, 0.f};
        }
        zz = mfma16(kf0, qf0, zz);
        zz = mfma16(kf1, qf1, zz);
        z[nt] = zz;
      }
      __builtin_amdgcn_s_setprio(0);
      mp += 64;

      // p = 2^S -> bf16, store into the P buffer (wave-private rows; reuse
      // across halves is ordered by same-wave lgkmcnt)
#pragma unroll
      for (int nt = 0; nt < 4; ++nt) {
        uint2 pv;
        pv.x = pack_rnd(ex2(z[nt][0]), ex2(z[nt][1]));
        pv.y = pack_rnd(ex2(z[nt][2]), ex2(z[nt][3]));
        *(uint2*)psp[nt] = pv;
      }

      // P A-frags (wave-private rows), then O += P V ; l += P * ones
      const bf16x8 pf0 = ld_frag(pf0p);
      const bf16x8 pf1 = ld_frag(pf1p);
      __builtin_amdgcn_s_setprio(1);
#pragma unroll
      for (int dt = 0; dt < 4; ++dt) {
        const bf16x8 vf0 = ld_frag(vf0p[dt] + ho);
        const bf16x8 vf1 = ld_frag(vf1p[dt] + ho);
        O[dt] = mfma16(pf0, vf0, O[dt]);
        O[dt] = mfma16(pf1, vf1, O[dt]);
      }
      O4 = mfma16(pf0, onesf, O4);
      O4 = mfma16(pf1, onesf, O4);
      __builtin_amdgcn_s_setprio(0);
    }
  }

  // l in col-0 lanes of each quad; epilogue ctx[b,q,h*64+d] = O / l
  float inv[4];
#pragma unroll
  for (int r = 0; r < 4; ++r)
    inv[r] = 1.0f / __shfl(O4[r], lane & 48, 64);

#pragma unroll
  for (int dt = 0; dt < 4; ++dt)
#pragma unroll
    for (int r = 0; r < 4; ++r) {
      const int gq = b * SEQ + q0 + w * 16 + quad * 4 + r;
      const int gd = h * 64 + dt * 16 + l16;
      ctx[(size_t)gq * D_MODEL + gd] = f2bf(O[dt][r] * inv[r]);
    }
}

// ---------- host ----------
extern "C" void kernel_launch(void* const* d_in, const int* in_sizes, int n_in,
                              void* d_out, int out_size, void* d_ws, size_t ws_size,
                              hipStream_t stream) {
  (void)in_sizes; (void)n_in; (void)out_size; (void)ws_size;
  const float* x    = (const float*)d_in[0];
  const float* y    = (const float*)d_in[1];
  const float* mask = (const float*)d_in[2];
  const float* Wq   = (const float*)d_in[3];
  const float* bq   = (const float*)d_in[4];
  const float* Wk   = (const float*)d_in[5];
  const float* bk   = (const float*)d_in[6];
  const float* Wv   = (const float*)d_in[7];
  const float* bv   = (const float*)d_in[8];
  const float* Wo   = (const float*)d_in[9];
  const float* bo   = (const float*)d_in[10];
  float* out = (float*)d_out;

  // 56 MB + 256 B workspace, aliased by lifetime. attn's slow path reads
  // mask f32 directly; d_out is written only by oproj.
  const size_t M4 = (size_t)4096 * 1024;   // 4M u16 = 8 MB
  const size_t M1 = (size_t)1024 * 1024;   // 1M u16 = 2 MB
  u16* qbuf  = (u16*)d_ws;         // [0,8)   qkv -> attn
  u16* kbuf  = qbuf + M4;          // [8,16)  qkv -> attn
  u16* vt    = kbuf + M4;          // [16,24) qkv (transposed) -> attn
  u16* cbuf  = vt + M4;            // [24,32) attn -> oproj
  u16* wob   = cbuf + M4;          // [32,34) qkv(filler) -> oproj
  u16* xb    = wob + M1;           // [34,42) pre -> qkv
  u16* yb    = xb + M4;            // [42,50) pre -> qkv
  u16* wqb   = yb + M4;            // [50,52) pre -> qkv
  u16* wkb   = wqb + M1;           // [52,54)
  u16* wvb   = wkb + M1;           // [54,56)
  u32* flags = (u32*)(wvb + M1);   // [56MB, +256B) mask-tile bits -> attn

  hipMemsetAsync(flags, 0, 64 * sizeof(u32), stream);
  pre_kernel<<<dim3(5632, 1, 1), 256, 0, stream>>>(
      x, y, Wq, Wk, Wv, xb, yb, wqb, wkb, wvb);
  qkv_kernel<<<dim3(32, 44, 1), 256, 0, stream>>>(xb, yb, wqb, wkb, wvb,
                                                  bq, bk, bv, mask, Wo,
                                                  qbuf, kbuf, vt, wob, flags);
  attn_kernel<<<dim3(NHEAD, 32, 2), 256, 0, stream>>>(qbuf, kbuf, vt, mask, flags, cbuf);
  oproj_kernel<<<dim3(32, 16, 1), 256, 0, stream>>>(cbuf, wob, bo, out);
}